// Round 9
// baseline (309.686 us; speedup 1.0000x reference)
//
#include <hip/hip_runtime.h>
#include <hip/hip_fp8.h>

typedef __attribute__((ext_vector_type(8))) short short8;
typedef __attribute__((ext_vector_type(4))) float floatx4;
typedef __attribute__((ext_vector_type(8))) int int8v;
typedef __attribute__((ext_vector_type(4))) int int4v;

#define LDS_PTR(x) ((__attribute__((address_space(3))) unsigned int*)(x))
#define GLB_PTR(x) ((const __attribute__((address_space(1))) unsigned int*)(x))

__device__ __forceinline__ unsigned short f2bf(float f) {
    unsigned int u = __float_as_uint(f);
    unsigned int r = (u + 0x7FFFu + ((u >> 16) & 1u)) >> 16;
    return (unsigned short)r;
}
__device__ __forceinline__ unsigned char f2fp8(float f) {
    __hip_fp8_e4m3 v(f);
    return (unsigned char)v.__x;
}
__device__ __forceinline__ float fp82f(unsigned int u) {
    __hip_fp8_e4m3 v;
    v.__x = (__hip_fp8_storage_t)(u & 0xFF);
    return (float)v;
}

// ---------------------------------------------------------------------------
// Fused post-side prep (one read of post_spikes & post_trace):
//   out_post_trace = S + dp*T (fp32, native)
//   At[p][k]   = fp8(S^T)   k in [0,B)      (RAW spikes)
//   At[p][B+k] = fp8(T^T)                   (RAW trace — dp folded into s)
// ---------------------------------------------------------------------------
__global__ __launch_bounds__(256) void prep_post_kernel(
    const float* __restrict__ S, const float* __restrict__ T,
    float* __restrict__ traceOut, unsigned char* __restrict__ At,
    int C, int K2, int Bsz, float dp)
{
    __shared__ float sT[64][65];
    __shared__ float tT[64][65];
    const int t = threadIdx.x;
    const int r0 = blockIdx.y * 64, c0 = blockIdx.x * 64;
#pragma unroll
    for (int i = 0; i < 4; ++i) {
        int rl = (t >> 4) + i * 16;
        int cl = (t & 15) * 4;
        size_t g = (size_t)(r0 + rl) * C + c0 + cl;
        float4 s4 = *(const float4*)&S[g];
        float4 t4 = *(const float4*)&T[g];
        float4 o;
        o.x = fmaf(t4.x, dp, s4.x); o.y = fmaf(t4.y, dp, s4.y);
        o.z = fmaf(t4.z, dp, s4.z); o.w = fmaf(t4.w, dp, s4.w);
        *(float4*)&traceOut[g] = o;
        sT[rl][cl + 0] = s4.x; sT[rl][cl + 1] = s4.y;
        sT[rl][cl + 2] = s4.z; sT[rl][cl + 3] = s4.w;
        tT[rl][cl + 0] = t4.x; tT[rl][cl + 1] = t4.y;
        tT[rl][cl + 2] = t4.z; tT[rl][cl + 3] = t4.w;
    }
    __syncthreads();
#pragma unroll
    for (int i = 0; i < 4; ++i) {
        int cl = (t >> 4) + i * 16;
        int rl = (t & 15) * 4;
        uchar4 a, b;
        a.x = f2fp8(sT[rl + 0][cl]); a.y = f2fp8(sT[rl + 1][cl]);
        a.z = f2fp8(sT[rl + 2][cl]); a.w = f2fp8(sT[rl + 3][cl]);
        b.x = f2fp8(tT[rl + 0][cl]); b.y = f2fp8(tT[rl + 1][cl]);
        b.z = f2fp8(tT[rl + 2][cl]); b.w = f2fp8(tT[rl + 3][cl]);
        *(uchar4*)&At[(size_t)(c0 + cl) * K2 + r0 + rl] = a;
        *(uchar4*)&At[(size_t)(c0 + cl) * K2 + Bsz + r0 + rl] = b;
    }
}

// ---------------------------------------------------------------------------
// Fused pre-side prep:
//   out_pre_trace = S + dp*T (fp32, native);  preBf = bf16(S) (native)
//   Bt[q][k]   = fp8(T^T)       (RAW pre_trace)
//   Bt[q][B+k] = fp8(-S^T)      (negated pre_spikes — sign folded)
// ---------------------------------------------------------------------------
__global__ __launch_bounds__(256) void prep_pre_kernel(
    const float* __restrict__ S, const float* __restrict__ T,
    float* __restrict__ traceOut, unsigned char* __restrict__ Bt,
    unsigned short* __restrict__ preBf,
    int C, int K2, int Bsz, float dp)
{
    __shared__ float sT[64][65];
    __shared__ float tT[64][65];
    const int t = threadIdx.x;
    const int r0 = blockIdx.y * 64, c0 = blockIdx.x * 64;
#pragma unroll
    for (int i = 0; i < 4; ++i) {
        int rl = (t >> 4) + i * 16;
        int cl = (t & 15) * 4;
        size_t g = (size_t)(r0 + rl) * C + c0 + cl;
        float4 s4 = *(const float4*)&S[g];
        float4 t4 = *(const float4*)&T[g];
        float4 o;
        o.x = fmaf(t4.x, dp, s4.x); o.y = fmaf(t4.y, dp, s4.y);
        o.z = fmaf(t4.z, dp, s4.z); o.w = fmaf(t4.w, dp, s4.w);
        *(float4*)&traceOut[g] = o;
        ushort4 pb = { f2bf(s4.x), f2bf(s4.y), f2bf(s4.z), f2bf(s4.w) };
        *(ushort4*)&preBf[g] = pb;
        sT[rl][cl + 0] = s4.x; sT[rl][cl + 1] = s4.y;
        sT[rl][cl + 2] = s4.z; sT[rl][cl + 3] = s4.w;
        tT[rl][cl + 0] = t4.x; tT[rl][cl + 1] = t4.y;
        tT[rl][cl + 2] = t4.z; tT[rl][cl + 3] = t4.w;
    }
    __syncthreads();
#pragma unroll
    for (int i = 0; i < 4; ++i) {
        int cl = (t >> 4) + i * 16;
        int rl = (t & 15) * 4;
        uchar4 a, b;
        a.x = f2fp8(tT[rl + 0][cl]); a.y = f2fp8(tT[rl + 1][cl]);
        a.z = f2fp8(tT[rl + 2][cl]); a.w = f2fp8(tT[rl + 3][cl]);
        b.x = f2fp8(-sT[rl + 0][cl]); b.y = f2fp8(-sT[rl + 1][cl]);
        b.z = f2fp8(-sT[rl + 2][cl]); b.w = f2fp8(-sT[rl + 3][cl]);
        *(uchar4*)&Bt[(size_t)(c0 + cl) * K2 + r0 + rl] = a;
        *(uchar4*)&Bt[(size_t)(c0 + cl) * K2 + Bsz + r0 + rl] = b;
    }
}

// ---------------------------------------------------------------------------
// Rate EMA from fp8-transposed post_spikes rows (At, k-contiguous).
// ---------------------------------------------------------------------------
__global__ __launch_bounds__(256) void rate_kernel(
    const unsigned char* __restrict__ At, const float* __restrict__ rr,
    float* __restrict__ new_rate, int K2, int Bsz)
{
    const int w = threadIdx.x >> 6, l = threadIdx.x & 63;
    const int p = blockIdx.x * 4 + w;
    const unsigned char* row = At + (size_t)p * K2;
    float s = 0.f;
    for (int k = l * 16; k < Bsz; k += 1024) {
        int4v v = *(const int4v*)&row[k];
#pragma unroll
        for (int wd = 0; wd < 4; ++wd) {
            unsigned int u = (unsigned int)v[wd];
            s += fp82f(u) + fp82f(u >> 8) + fp82f(u >> 16) + fp82f(u >> 24);
        }
    }
#pragma unroll
    for (int off = 32; off > 0; off >>= 1) s += __shfl_xor(s, off, 64);
    if (l == 0)
        new_rate[p] = rr[p] * 0.99f + 0.01f * (s / (float)Bsz);
}

// ---------------------------------------------------------------------------
// MX-fp8 dw GEMM — R9: full 8-phase-style fine interleave (T3+T4+T5).
// BM=256 x BN=128, BK=128, 512 threads (8 waves 4Mx2N, per-wave 64x64 =
// R4's proven per-wave shape). LDS ring of 3 x (lA 32K + lB 16K) = 144KB.
// Per K-tile: 4 phases, phase j = {ds_read frags (af[0..3]+bf[0] in ph0,
// bf[j] after) | stage 2 loads of tile t+2 | barrier | lgkmcnt(0)+schedbar |
// setprio(1) 4xMFMA setprio(0) | barrier}. Boundary: s_waitcnt vmcnt(6) —
// tile t+2's 6 loads stay in flight ACROSS the tile boundary (never 0 in
// steady state). Correctness rests only on boundary vmcnt+barrier: stage
// target buf (t+2)%3 is disjoint from compute buf t%3 and ready buf
// (t+1)%3, so phase barriers are performance-only.
// Epilogue: single-pass 256x128 f32 LDS tile (128KB of the 144KB), fully
// coalesced Wold read + homeo + clip + fp32/bf16 dual store.
// ---------------------------------------------------------------------------
__global__ __launch_bounds__(512) void dw_fp8_kernel(
    const unsigned char* __restrict__ A, const unsigned char* __restrict__ B,
    int K, int N, float s,
    const float* __restrict__ Wold, const float* __restrict__ rr,
    float* __restrict__ outF, unsigned short* __restrict__ outBf)
{
    constexpr int BM = 256, BN = 128, BK = 128;
    __shared__ unsigned char smem[147456];  // 3 x 48KB ring | 128KB f32 out tile

    const int t = threadIdx.x;              // 0..511
    const int l = t & 63;
    const int w = t >> 6;                   // 0..7
    const int wm = w >> 1, wn = w & 1;      // 4 M-waves x 2 N-waves
    const int bm = blockIdx.y, bn = blockIdx.x;

    floatx4 acc[4][4] = {};

    // stage groups: A-half0 (2 loads), A-half1 (2), B (2) — 6 loads/thread/tile
    auto stageA = [&](int buf, int k0, int half) {
        unsigned char* la = smem + buf * 49152;
#pragma unroll
        for (int i = 0; i < 2; ++i) {
            int ci = half * 1024 + i * 512 + t;   // 16B chunk in [0,2048)
            int r = ci >> 3, sc = ci & 7;
            int g = sc ^ (r & 7);                 // swizzled source sub-chunk
            const unsigned char* gp = A + (size_t)(bm * BM + r) * K + k0 + g * 16;
            __builtin_amdgcn_global_load_lds(GLB_PTR(gp),
                LDS_PTR(la + ci * 16), 16, 0, 0);
        }
    };
    auto stageB = [&](int buf, int k0) {
        unsigned char* lb = smem + buf * 49152 + 32768;
#pragma unroll
        for (int i = 0; i < 2; ++i) {
            int ci = i * 512 + t;                 // 16B chunk in [0,1024)
            int r = ci >> 3, sc = ci & 7;
            int g = sc ^ (r & 7);
            const unsigned char* gp = B + (size_t)(bn * BN + r) * K + k0 + g * 16;
            __builtin_amdgcn_global_load_lds(GLB_PTR(gp),
                LDS_PTR(lb + ci * 16), 16, 0, 0);
        }
    };

    const int kq = l >> 4;                  // k-quad 0..3
    const int m = l & 15;

    auto rdfrag = [&](const unsigned char* base, int row) {
        int s0 = (2 * kq) ^ (row & 7), s1 = (2 * kq + 1) ^ (row & 7);
        int4v lo = *(const int4v*)&base[row * 128 + s0 * 16];
        int4v hi = *(const int4v*)&base[row * 128 + s1 * 16];
        int8v r;
        r[0] = lo[0]; r[1] = lo[1]; r[2] = lo[2]; r[3] = lo[3];
        r[4] = hi[0]; r[5] = hi[1]; r[6] = hi[2]; r[7] = hi[3];
        return r;
    };

    const int nT = K / BK;                  // 16
    // prologue: tiles 0 and 1 fully staged; wait tile 0 (allow tile 1's 6)
    stageA(0, 0, 0); stageA(0, 0, 1); stageB(0, 0);
    stageA(1, BK, 0); stageA(1, BK, 1); stageB(1, BK);
    asm volatile("s_waitcnt vmcnt(6)" ::: "memory");
    __builtin_amdgcn_s_barrier();

    int c = 0;
    for (int tt = 0; tt < nT; ++tt) {
        const unsigned char* la = smem + c * 49152;
        const unsigned char* lb = smem + c * 49152 + 32768;
        int n2 = c + 2; if (n2 >= 3) n2 -= 3;
        const int k2 = (tt + 2) * BK;
        const bool doStage = (tt + 2 < nT);

        int8v af[4], bfj;

        // ---- phase 0: af[0..3] + bf[0]; MFMA column 0 ----
#pragma unroll
        for (int i = 0; i < 4; ++i)
            af[i] = rdfrag(la, wm * 64 + i * 16 + m);
        bfj = rdfrag(lb, wn * 64 + m);
        __builtin_amdgcn_s_barrier();
        asm volatile("s_waitcnt lgkmcnt(0)" ::: "memory");
        __builtin_amdgcn_sched_barrier(0);
        __builtin_amdgcn_s_setprio(1);
#pragma unroll
        for (int i = 0; i < 4; ++i)
            acc[i][0] = __builtin_amdgcn_mfma_scale_f32_16x16x128_f8f6f4(
                af[i], bfj, acc[i][0], 0, 0, 0, 0x7f, 0, 0x7f);
        __builtin_amdgcn_s_setprio(0);
        __builtin_amdgcn_s_barrier();

        // ---- phases 1..3: stage 2 loads | bf[j] | MFMA column j ----
#pragma unroll
        for (int j = 1; j < 4; ++j) {
            if (doStage) {
                if (j == 1)      stageA(n2, k2, 0);
                else if (j == 2) stageA(n2, k2, 1);
                else             stageB(n2, k2);
            }
            bfj = rdfrag(lb, wn * 64 + j * 16 + m);
            __builtin_amdgcn_s_barrier();
            asm volatile("s_waitcnt lgkmcnt(0)" ::: "memory");
            __builtin_amdgcn_sched_barrier(0);
            __builtin_amdgcn_s_setprio(1);
#pragma unroll
            for (int i = 0; i < 4; ++i)
                acc[i][j] = __builtin_amdgcn_mfma_scale_f32_16x16x128_f8f6f4(
                    af[i], bfj, acc[i][j], 0, 0, 0, 0x7f, 0, 0x7f);
            __builtin_amdgcn_s_setprio(0);
            if (j < 3) __builtin_amdgcn_s_barrier();
        }

        // ---- tile boundary: counted wait — t+2's 6 loads stay in flight ----
        if (doStage) asm volatile("s_waitcnt vmcnt(6)" ::: "memory");
        else         asm volatile("s_waitcnt vmcnt(0)" ::: "memory");
        __builtin_amdgcn_s_barrier();
        c = (c + 1 == 3) ? 0 : c + 1;
    }

    // ---- coalesced epilogue: acc -> 256x128 f32 LDS tile -> global ----
    __syncthreads();
    float* sOut = (float*)smem;      // 256 x 128 f32 = 128KB (of 144KB)
#pragma unroll
    for (int i = 0; i < 4; ++i)
#pragma unroll
        for (int r = 0; r < 4; ++r) {
            const int row = wm * 64 + i * 16 + (l >> 4) * 4 + r;
#pragma unroll
            for (int j = 0; j < 4; ++j) {
                const int col = wn * 64 + j * 16 + (l & 15);
                sOut[row * 128 + col] = acc[i][j][r];
            }
        }
    __syncthreads();

    const int pBase = bm * BM;
    const int qBase = bn * BN;
#pragma unroll
    for (int k = 0; k < 16; ++k) {
        const int ci = k * 512 + t;          // float4 chunk index 0..8191
        const int row = ci >> 5;             // 0..255
        const int cc = (ci & 31) * 4;        // 0..124
        const int p = pBase + row;
        const int q = qBase + cc;
        const size_t idx = (size_t)p * N + q;
        float4 a4 = *(const float4*)&sOut[ci * 4];
        float4 w4 = *(const float4*)&Wold[idx];
        const float hp = -0.001f * (rr[p] - 0.1f);
        float4 v;
        v.x = fminf(fmaxf(fmaf(s, a4.x, w4.x + hp), 0.f), 1.f);
        v.y = fminf(fmaxf(fmaf(s, a4.y, w4.y + hp), 0.f), 1.f);
        v.z = fminf(fmaxf(fmaf(s, a4.z, w4.z + hp), 0.f), 1.f);
        v.w = fminf(fmaxf(fmaf(s, a4.w, w4.w + hp), 0.f), 1.f);
        *(float4*)&outF[idx] = v;
        ushort4 b4 = { f2bf(v.x), f2bf(v.y), f2bf(v.z), f2bf(v.w) };
        *(ushort4*)&outBf[idx] = b4;
    }
}

// ---------------------------------------------------------------------------
// BT-form bf16 MFMA GEMM (current = pre @ W^T) — R4-EXACT revert (its best
// measured config; R6/R7/R8 variants all within noise or worse).
// 512 threads / 8 waves (2x4 wave grid), 128x128 tile, BK=128, 128KB dbuf.
// ---------------------------------------------------------------------------
__global__ __launch_bounds__(512) void mfma_gemm_bt(
    const unsigned short* __restrict__ A,
    const unsigned short* __restrict__ Bm,
    int K, int N, float* __restrict__ outF)
{
    constexpr int BM = 128, BN = 128, BK = 128;
    __shared__ unsigned char smem[131072];  // 2 bufs x (lA 32K + lB 32K)

    const int t = threadIdx.x;
    const int l = t & 63;
    const int w = t >> 6;                   // 0..7
    const int wm = w >> 2, wn = w & 3;      // 2 row-halves x 4 col-quarters
    const int bm = blockIdx.y, bn = blockIdx.x;

    floatx4 acc[4][2] = {};                 // per wave: 64 rows x 32 cols

    auto stage = [&](int buf, int k0) {
        unsigned short* la = (unsigned short*)(smem + buf * 65536);
        unsigned short* lb = (unsigned short*)(smem + buf * 65536 + 32768);
#pragma unroll
        for (int i = 0; i < 4; ++i) {
            int ci = i * 512 + t;            // 16B chunk 0..2047; 16 chunks/row
            int r = ci >> 4, sc = ci & 15;
            int g = sc ^ (r & 15);           // swizzled source sub-chunk
            const unsigned short* gpA =
                A + (size_t)(bm * BM + r) * K + k0 + g * 8;
            __builtin_amdgcn_global_load_lds(GLB_PTR(gpA),
                LDS_PTR(la + ci * 8), 16, 0, 0);
            const unsigned short* gpB =
                Bm + (size_t)(bn * BN + r) * K + k0 + g * 8;
            __builtin_amdgcn_global_load_lds(GLB_PTR(gpB),
                LDS_PTR(lb + ci * 8), 16, 0, 0);
        }
    };

    stage(0, 0);
    __syncthreads();                 // prologue drain

    const int nT = K / BK;
    int cur = 0;
    for (int tt = 0; tt < nT; ++tt) {
        if (tt + 1 < nT) stage(cur ^ 1, (tt + 1) * BK);   // prefetch next tile

        const unsigned short* la = (const unsigned short*)(smem + cur * 65536);
        const unsigned short* lb = (const unsigned short*)(smem + cur * 65536 + 32768);
        const int q = l >> 4;      // 16B chunk within 64B k-slice
        const int m = l & 15;
#pragma unroll
        for (int ks = 0; ks < 4; ++ks) {
            short8 af[4], bf[2];
            const int c2 = ks * 4 + q;       // chunk 0..15
#pragma unroll
            for (int i = 0; i < 4; ++i) {
                int ra = wm * 64 + i * 16 + m;
                af[i] = *(const short8*)&la[ra * BK + ((c2 ^ (ra & 15)) * 8)];
            }
#pragma unroll
            for (int j = 0; j < 2; ++j) {
                int rb = wn * 32 + j * 16 + m;
                bf[j] = *(const short8*)&lb[rb * BK + ((c2 ^ (rb & 15)) * 8)];
            }
#pragma unroll
            for (int i = 0; i < 4; ++i)
#pragma unroll
                for (int j = 0; j < 2; ++j)
                    acc[i][j] = __builtin_amdgcn_mfma_f32_16x16x32_bf16(
                        af[i], bf[j], acc[i][j], 0, 0, 0);
        }

        asm volatile("s_waitcnt vmcnt(0)" ::: "memory");
        __builtin_amdgcn_s_barrier();
        cur ^= 1;
    }

    // ---- coalesced epilogue ----
    __syncthreads();
    float* sOut = (float*)smem;      // 128 x 128 f32 = 64KB (fits in 128KB)
#pragma unroll
    for (int i = 0; i < 4; ++i)
#pragma unroll
        for (int r = 0; r < 4; ++r) {
            const int row = wm * 64 + i * 16 + (l >> 4) * 4 + r;
#pragma unroll
            for (int j = 0; j < 2; ++j) {
                const int col = wn * 32 + j * 16 + (l & 15);
                sOut[row * 128 + col] = acc[i][j][r];
            }
        }
    __syncthreads();

    const int pBase = bm * BM;
    const int qBase = bn * BN;
#pragma unroll
    for (int k = 0; k < 8; ++k) {
        const int ci = k * 512 + t;          // float4 chunk 0..4095
        const int row = ci >> 5;             // 0..127
        const int cc = (ci & 31) * 4;
        float4 v = *(const float4*)&sOut[ci * 4];
        *(float4*)&outF[(size_t)(pBase + row) * N + qBase + cc] = v;
    }
}

// ---------------------------------------------------------------------------
extern "C" void kernel_launch(void* const* d_in, const int* in_sizes, int n_in,
                              void* d_out, int out_size, void* d_ws, size_t ws_size,
                              hipStream_t stream)
{
    const float* pre_spikes   = (const float*)d_in[0];
    const float* post_spikes  = (const float*)d_in[1];
    const float* weights      = (const float*)d_in[2];
    const float* pre_trace    = (const float*)d_in[3];
    const float* post_trace   = (const float*)d_in[4];
    const float* running_rate = (const float*)d_in[5];

    const int POST = in_sizes[5];
    const int PRE  = in_sizes[2] / POST;
    const int Bsz  = in_sizes[0] / PRE;
    const int K2   = 2 * Bsz;

    const size_t nCur   = (size_t)Bsz * POST;
    const size_t nW     = (size_t)POST * PRE;
    const size_t nPreT  = (size_t)Bsz * PRE;
    const size_t nPostT = (size_t)Bsz * POST;

    float* out_current    = (float*)d_out;
    float* out_weights    = out_current + nCur;
    float* out_pre_trace  = out_weights + nW;
    float* out_post_trace = out_pre_trace + nPreT;
    float* out_rate       = out_post_trace + nPostT;

    unsigned char* At     = (unsigned char*)d_ws;        // (POST x K2) fp8
    unsigned char* Bt     = At + (size_t)POST * K2;      // (PRE  x K2) fp8
    unsigned short* preBf = (unsigned short*)(Bt + (size_t)PRE * K2); // (B x PRE) bf16
    unsigned short* wBf   = preBf + nPreT;               // (POST x PRE) bf16

    const float dp = 0.95122942450071400910f;            // exp(-1/20)
    const float s  = dp * (0.01f / (float)Bsz);          // A+/-. * dp / B

    // 1) fused prep: traces + fp8 GEMM operands (one read per input)
    prep_post_kernel<<<dim3(POST / 64, Bsz / 64), 256, 0, stream>>>(
        post_spikes, post_trace, out_post_trace, At, POST, K2, Bsz, dp);
    prep_pre_kernel<<<dim3(PRE / 64, Bsz / 64), 256, 0, stream>>>(
        pre_spikes, pre_trace, out_pre_trace, Bt, preBf, PRE, K2, Bsz, dp);

    // 2) rate EMA
    rate_kernel<<<POST / 4, 256, 0, stream>>>(
        At, running_rate, out_rate, K2, Bsz);

    // 3) dw GEMM in MX-fp8 (M=POST, N=PRE, K=2B) + fused w/homeo/clip
    dw_fp8_kernel<<<dim3(PRE / 128, POST / 256), 512, 0, stream>>>(
        At, Bt, K2, PRE, s, weights, running_rate, out_weights, wBf);

    // 4) current GEMM bf16 (M=B, N=POST, K=PRE): pre_spikes @ new_w^T
    mfma_gemm_bt<<<dim3(POST / 128, Bsz / 128), 512, 0, stream>>>(
        preBf, wBf, PRE, POST, out_current);
}

// Round 10
// 298.334 us; speedup vs baseline: 1.0381x; 1.0381x over previous
//
#include <hip/hip_runtime.h>
#include <hip/hip_fp8.h>

typedef __attribute__((ext_vector_type(8))) short short8;
typedef __attribute__((ext_vector_type(4))) float floatx4;
typedef __attribute__((ext_vector_type(8))) int int8v;
typedef __attribute__((ext_vector_type(4))) int int4v;

#define LDS_PTR(x) ((__attribute__((address_space(3))) unsigned int*)(x))
#define GLB_PTR(x) ((const __attribute__((address_space(1))) unsigned int*)(x))

__device__ __forceinline__ unsigned short f2bf(float f) {
    unsigned int u = __float_as_uint(f);
    unsigned int r = (u + 0x7FFFu + ((u >> 16) & 1u)) >> 16;
    return (unsigned short)r;
}
__device__ __forceinline__ unsigned char f2fp8(float f) {
    __hip_fp8_e4m3 v(f);
    return (unsigned char)v.__x;
}
__device__ __forceinline__ float fp82f(unsigned int u) {
    __hip_fp8_e4m3 v;
    v.__x = (__hip_fp8_storage_t)(u & 0xFF);
    return (float)v;
}

// ---------------------------------------------------------------------------
// Fused post-side prep (one read of post_spikes & post_trace):
//   out_post_trace = S + dp*T (fp32, native)
//   At[p][k]   = fp8(S^T)   k in [0,B)      (RAW spikes)
//   At[p][B+k] = fp8(T^T)                   (RAW trace — dp folded into s)
// ---------------------------------------------------------------------------
__global__ __launch_bounds__(256) void prep_post_kernel(
    const float* __restrict__ S, const float* __restrict__ T,
    float* __restrict__ traceOut, unsigned char* __restrict__ At,
    int C, int K2, int Bsz, float dp)
{
    __shared__ float sT[64][65];
    __shared__ float tT[64][65];
    const int t = threadIdx.x;
    const int r0 = blockIdx.y * 64, c0 = blockIdx.x * 64;
#pragma unroll
    for (int i = 0; i < 4; ++i) {
        int rl = (t >> 4) + i * 16;
        int cl = (t & 15) * 4;
        size_t g = (size_t)(r0 + rl) * C + c0 + cl;
        float4 s4 = *(const float4*)&S[g];
        float4 t4 = *(const float4*)&T[g];
        float4 o;
        o.x = fmaf(t4.x, dp, s4.x); o.y = fmaf(t4.y, dp, s4.y);
        o.z = fmaf(t4.z, dp, s4.z); o.w = fmaf(t4.w, dp, s4.w);
        *(float4*)&traceOut[g] = o;
        sT[rl][cl + 0] = s4.x; sT[rl][cl + 1] = s4.y;
        sT[rl][cl + 2] = s4.z; sT[rl][cl + 3] = s4.w;
        tT[rl][cl + 0] = t4.x; tT[rl][cl + 1] = t4.y;
        tT[rl][cl + 2] = t4.z; tT[rl][cl + 3] = t4.w;
    }
    __syncthreads();
#pragma unroll
    for (int i = 0; i < 4; ++i) {
        int cl = (t >> 4) + i * 16;
        int rl = (t & 15) * 4;
        uchar4 a, b;
        a.x = f2fp8(sT[rl + 0][cl]); a.y = f2fp8(sT[rl + 1][cl]);
        a.z = f2fp8(sT[rl + 2][cl]); a.w = f2fp8(sT[rl + 3][cl]);
        b.x = f2fp8(tT[rl + 0][cl]); b.y = f2fp8(tT[rl + 1][cl]);
        b.z = f2fp8(tT[rl + 2][cl]); b.w = f2fp8(tT[rl + 3][cl]);
        *(uchar4*)&At[(size_t)(c0 + cl) * K2 + r0 + rl] = a;
        *(uchar4*)&At[(size_t)(c0 + cl) * K2 + Bsz + r0 + rl] = b;
    }
}

// ---------------------------------------------------------------------------
// Fused pre-side prep:
//   out_pre_trace = S + dp*T (fp32, native);  preBf = bf16(S) (native)
//   Bt[q][k]   = fp8(T^T)       (RAW pre_trace)
//   Bt[q][B+k] = fp8(-S^T)      (negated pre_spikes — sign folded)
// ---------------------------------------------------------------------------
__global__ __launch_bounds__(256) void prep_pre_kernel(
    const float* __restrict__ S, const float* __restrict__ T,
    float* __restrict__ traceOut, unsigned char* __restrict__ Bt,
    unsigned short* __restrict__ preBf,
    int C, int K2, int Bsz, float dp)
{
    __shared__ float sT[64][65];
    __shared__ float tT[64][65];
    const int t = threadIdx.x;
    const int r0 = blockIdx.y * 64, c0 = blockIdx.x * 64;
#pragma unroll
    for (int i = 0; i < 4; ++i) {
        int rl = (t >> 4) + i * 16;
        int cl = (t & 15) * 4;
        size_t g = (size_t)(r0 + rl) * C + c0 + cl;
        float4 s4 = *(const float4*)&S[g];
        float4 t4 = *(const float4*)&T[g];
        float4 o;
        o.x = fmaf(t4.x, dp, s4.x); o.y = fmaf(t4.y, dp, s4.y);
        o.z = fmaf(t4.z, dp, s4.z); o.w = fmaf(t4.w, dp, s4.w);
        *(float4*)&traceOut[g] = o;
        ushort4 pb = { f2bf(s4.x), f2bf(s4.y), f2bf(s4.z), f2bf(s4.w) };
        *(ushort4*)&preBf[g] = pb;
        sT[rl][cl + 0] = s4.x; sT[rl][cl + 1] = s4.y;
        sT[rl][cl + 2] = s4.z; sT[rl][cl + 3] = s4.w;
        tT[rl][cl + 0] = t4.x; tT[rl][cl + 1] = t4.y;
        tT[rl][cl + 2] = t4.z; tT[rl][cl + 3] = t4.w;
    }
    __syncthreads();
#pragma unroll
    for (int i = 0; i < 4; ++i) {
        int cl = (t >> 4) + i * 16;
        int rl = (t & 15) * 4;
        uchar4 a, b;
        a.x = f2fp8(tT[rl + 0][cl]); a.y = f2fp8(tT[rl + 1][cl]);
        a.z = f2fp8(tT[rl + 2][cl]); a.w = f2fp8(tT[rl + 3][cl]);
        b.x = f2fp8(-sT[rl + 0][cl]); b.y = f2fp8(-sT[rl + 1][cl]);
        b.z = f2fp8(-sT[rl + 2][cl]); b.w = f2fp8(-sT[rl + 3][cl]);
        *(uchar4*)&Bt[(size_t)(c0 + cl) * K2 + r0 + rl] = a;
        *(uchar4*)&Bt[(size_t)(c0 + cl) * K2 + Bsz + r0 + rl] = b;
    }
}

// ---------------------------------------------------------------------------
// Rate EMA from fp8-transposed post_spikes rows (At, k-contiguous).
// ---------------------------------------------------------------------------
__global__ __launch_bounds__(256) void rate_kernel(
    const unsigned char* __restrict__ At, const float* __restrict__ rr,
    float* __restrict__ new_rate, int K2, int Bsz)
{
    const int w = threadIdx.x >> 6, l = threadIdx.x & 63;
    const int p = blockIdx.x * 4 + w;
    const unsigned char* row = At + (size_t)p * K2;
    float s = 0.f;
    for (int k = l * 16; k < Bsz; k += 1024) {
        int4v v = *(const int4v*)&row[k];
#pragma unroll
        for (int wd = 0; wd < 4; ++wd) {
            unsigned int u = (unsigned int)v[wd];
            s += fp82f(u) + fp82f(u >> 8) + fp82f(u >> 16) + fp82f(u >> 24);
        }
    }
#pragma unroll
    for (int off = 32; off > 0; off >>= 1) s += __shfl_xor(s, off, 64);
    if (l == 0)
        new_rate[p] = rr[p] * 0.99f + 0.01f * (s / (float)Bsz);
}

// ---------------------------------------------------------------------------
// MX-fp8 dw GEMM (R4-EXACT — empirical optimum: 68.4-71.2us across rounds).
// 128x128 tile, BK=128, mfma_scale_f32_16x16x128_f8f6f4, unit e8m0 scales.
// XOR-swizzled LDS; 2-phase double-buffered K-loop; coalesced epilogue via
// LDS f32 tile. Session-verified constraints: LDS <= 64KB at 256 threads
// (R5: 96KB -> 1 blk/CU -> -33us); no register Wold preload (R3: VGPR 136
// -> occupancy drop -> -20us); K-loop at ~1550 TF = m97-structure MX-fp8
// ceiling (m148); 8-phase fine interleave regresses here (R9: L3-resident
// operands + 16 K-tiles -> barrier cost > latency hidden).
// ---------------------------------------------------------------------------
__global__ __launch_bounds__(256) void dw_fp8_kernel(
    const unsigned char* __restrict__ A, const unsigned char* __restrict__ B,
    int K, int N, float s,
    const float* __restrict__ Wold, const float* __restrict__ rr,
    float* __restrict__ outF, unsigned short* __restrict__ outBf)
{
    constexpr int BM = 128, BN = 128, BK = 128;
    __shared__ unsigned char smem[65536];   // 2x(lA 16K) + 2x(lB 16K) | f32 out tile

    const int t = threadIdx.x;
    const int l = t & 63;
    const int w = t >> 6;
    const int wm = w >> 1, wn = w & 1;
    const int bm = blockIdx.y, bn = blockIdx.x;

    floatx4 acc[4][4] = {};

    auto stage = [&](int buf, int k0) {
        unsigned char* la = smem + buf * 16384;
        unsigned char* lb = smem + 32768 + buf * 16384;
#pragma unroll
        for (int i = 0; i < 4; ++i) {
            int ci = i * 256 + t;            // 16B chunk index (lane-linear)
            int r = ci >> 3, sc = ci & 7;
            int g = sc ^ (r & 7);            // swizzled source sub-chunk
            const unsigned char* gpA = A + (size_t)(bm * BM + r) * K + k0 + g * 16;
            __builtin_amdgcn_global_load_lds(GLB_PTR(gpA),
                LDS_PTR(&la[ci * 16]), 16, 0, 0);
            const unsigned char* gpB = B + (size_t)(bn * BN + r) * K + k0 + g * 16;
            __builtin_amdgcn_global_load_lds(GLB_PTR(gpB),
                LDS_PTR(&lb[ci * 16]), 16, 0, 0);
        }
    };

    stage(0, 0);
    __syncthreads();                 // prologue drain

    const int nT = K / BK;
    int cur = 0;
    for (int tt = 0; tt < nT; ++tt) {
        if (tt + 1 < nT) stage(cur ^ 1, (tt + 1) * BK);   // prefetch next tile

        const unsigned char* la = smem + cur * 16384;
        const unsigned char* lb = smem + 32768 + cur * 16384;
        const int c = l >> 4;      // k-quad: covers k bytes [c*32, c*32+32)
        const int m = l & 15;
        int8v af[4], bf[4];
#pragma unroll
        for (int i = 0; i < 4; ++i) {
            int ra = wm * 64 + i * 16 + m;
            int s0 = (2 * c) ^ (ra & 7), s1 = (2 * c + 1) ^ (ra & 7);
            int4v lo = *(const int4v*)&la[ra * BK + s0 * 16];
            int4v hi = *(const int4v*)&la[ra * BK + s1 * 16];
            af[i][0] = lo[0]; af[i][1] = lo[1]; af[i][2] = lo[2]; af[i][3] = lo[3];
            af[i][4] = hi[0]; af[i][5] = hi[1]; af[i][6] = hi[2]; af[i][7] = hi[3];
        }
#pragma unroll
        for (int j = 0; j < 4; ++j) {
            int rb = wn * 64 + j * 16 + m;
            int s0 = (2 * c) ^ (rb & 7), s1 = (2 * c + 1) ^ (rb & 7);
            int4v lo = *(const int4v*)&lb[rb * BK + s0 * 16];
            int4v hi = *(const int4v*)&lb[rb * BK + s1 * 16];
            bf[j][0] = lo[0]; bf[j][1] = lo[1]; bf[j][2] = lo[2]; bf[j][3] = lo[3];
            bf[j][4] = hi[0]; bf[j][5] = hi[1]; bf[j][6] = hi[2]; bf[j][7] = hi[3];
        }
#pragma unroll
        for (int i = 0; i < 4; ++i)
#pragma unroll
            for (int j = 0; j < 4; ++j)
                acc[i][j] = __builtin_amdgcn_mfma_scale_f32_16x16x128_f8f6f4(
                    af[i], bf[j], acc[i][j], 0, 0, 0, 0x7f, 0, 0x7f);

        asm volatile("s_waitcnt vmcnt(0)" ::: "memory");
        __builtin_amdgcn_s_barrier();
        cur ^= 1;
    }

    // ---- coalesced epilogue: acc -> LDS f32 tile -> row-major global ----
    __syncthreads();
    float* sOut = (float*)smem;      // 128 x 128 f32 = 64KB
#pragma unroll
    for (int i = 0; i < 4; ++i)
#pragma unroll
        for (int r = 0; r < 4; ++r) {
            const int row = wm * 64 + i * 16 + (l >> 4) * 4 + r;
#pragma unroll
            for (int j = 0; j < 4; ++j) {
                const int col = wn * 64 + j * 16 + (l & 15);
                sOut[row * 128 + col] = acc[i][j][r];
            }
        }
    __syncthreads();

    const int pBase = bm * BM;
    const int qBase = bn * BN;
#pragma unroll
    for (int k = 0; k < 16; ++k) {
        const int ci = k * 256 + t;          // float4 chunk index 0..4095
        const int row = ci >> 5;             // 0..127
        const int cc = (ci & 31) * 4;        // 0..124
        const int p = pBase + row;
        const int q = qBase + cc;
        const size_t idx = (size_t)p * N + q;
        float4 a4 = *(const float4*)&sOut[ci * 4];
        float4 w4 = *(const float4*)&Wold[idx];
        const float hp = -0.001f * (rr[p] - 0.1f);
        float4 v;
        v.x = fminf(fmaxf(fmaf(s, a4.x, w4.x + hp), 0.f), 1.f);
        v.y = fminf(fmaxf(fmaf(s, a4.y, w4.y + hp), 0.f), 1.f);
        v.z = fminf(fmaxf(fmaf(s, a4.z, w4.z + hp), 0.f), 1.f);
        v.w = fminf(fmaxf(fmaf(s, a4.w, w4.w + hp), 0.f), 1.f);
        *(float4*)&outF[idx] = v;
        ushort4 b4 = { f2bf(v.x), f2bf(v.y), f2bf(v.z), f2bf(v.w) };
        *(ushort4*)&outBf[idx] = b4;
    }
}

// ---------------------------------------------------------------------------
// BT-form bf16 MFMA GEMM (current = pre @ W^T) — R4-EXACT (best measured;
// R6 k-split, R7 TLP-doubling, R8 counted-vmcnt ring all null or worse).
// 512 threads / 8 waves (2x4 wave grid), 128x128 tile, BK=128, 128KB dbuf.
// ---------------------------------------------------------------------------
__global__ __launch_bounds__(512) void mfma_gemm_bt(
    const unsigned short* __restrict__ A,
    const unsigned short* __restrict__ Bm,
    int K, int N, float* __restrict__ outF)
{
    constexpr int BM = 128, BN = 128, BK = 128;
    __shared__ unsigned char smem[131072];  // 2 bufs x (lA 32K + lB 32K)

    const int t = threadIdx.x;
    const int l = t & 63;
    const int w = t >> 6;                   // 0..7
    const int wm = w >> 2, wn = w & 3;      // 2 row-halves x 4 col-quarters
    const int bm = blockIdx.y, bn = blockIdx.x;

    floatx4 acc[4][2] = {};                 // per wave: 64 rows x 32 cols

    auto stage = [&](int buf, int k0) {
        unsigned short* la = (unsigned short*)(smem + buf * 65536);
        unsigned short* lb = (unsigned short*)(smem + buf * 65536 + 32768);
#pragma unroll
        for (int i = 0; i < 4; ++i) {
            int ci = i * 512 + t;            // 16B chunk 0..2047; 16 chunks/row
            int r = ci >> 4, sc = ci & 15;
            int g = sc ^ (r & 15);           // swizzled source sub-chunk
            const unsigned short* gpA =
                A + (size_t)(bm * BM + r) * K + k0 + g * 8;
            __builtin_amdgcn_global_load_lds(GLB_PTR(gpA),
                LDS_PTR(la + ci * 8), 16, 0, 0);
            const unsigned short* gpB =
                Bm + (size_t)(bn * BN + r) * K + k0 + g * 8;
            __builtin_amdgcn_global_load_lds(GLB_PTR(gpB),
                LDS_PTR(lb + ci * 8), 16, 0, 0);
        }
    };

    stage(0, 0);
    __syncthreads();                 // prologue drain

    const int nT = K / BK;
    int cur = 0;
    for (int tt = 0; tt < nT; ++tt) {
        if (tt + 1 < nT) stage(cur ^ 1, (tt + 1) * BK);   // prefetch next tile

        const unsigned short* la = (const unsigned short*)(smem + cur * 65536);
        const unsigned short* lb = (const unsigned short*)(smem + cur * 65536 + 32768);
        const int q = l >> 4;      // 16B chunk within 64B k-slice
        const int m = l & 15;
#pragma unroll
        for (int ks = 0; ks < 4; ++ks) {
            short8 af[4], bf[2];
            const int c2 = ks * 4 + q;       // chunk 0..15
#pragma unroll
            for (int i = 0; i < 4; ++i) {
                int ra = wm * 64 + i * 16 + m;
                af[i] = *(const short8*)&la[ra * BK + ((c2 ^ (ra & 15)) * 8)];
            }
#pragma unroll
            for (int j = 0; j < 2; ++j) {
                int rb = wn * 32 + j * 16 + m;
                bf[j] = *(const short8*)&lb[rb * BK + ((c2 ^ (rb & 15)) * 8)];
            }
#pragma unroll
            for (int i = 0; i < 4; ++i)
#pragma unroll
                for (int j = 0; j < 2; ++j)
                    acc[i][j] = __builtin_amdgcn_mfma_f32_16x16x32_bf16(
                        af[i], bf[j], acc[i][j], 0, 0, 0);
        }

        asm volatile("s_waitcnt vmcnt(0)" ::: "memory");
        __builtin_amdgcn_s_barrier();
        cur ^= 1;
    }

    // ---- coalesced epilogue ----
    __syncthreads();
    float* sOut = (float*)smem;      // 128 x 128 f32 = 64KB (fits in 128KB)
#pragma unroll
    for (int i = 0; i < 4; ++i)
#pragma unroll
        for (int r = 0; r < 4; ++r) {
            const int row = wm * 64 + i * 16 + (l >> 4) * 4 + r;
#pragma unroll
            for (int j = 0; j < 2; ++j) {
                const int col = wn * 32 + j * 16 + (l & 15);
                sOut[row * 128 + col] = acc[i][j][r];
            }
        }
    __syncthreads();

    const int pBase = bm * BM;
    const int qBase = bn * BN;
#pragma unroll
    for (int k = 0; k < 8; ++k) {
        const int ci = k * 512 + t;          // float4 chunk 0..4095
        const int row = ci >> 5;             // 0..127
        const int cc = (ci & 31) * 4;
        float4 v = *(const float4*)&sOut[ci * 4];
        *(float4*)&outF[(size_t)(pBase + row) * N + qBase + cc] = v;
    }
}

// ---------------------------------------------------------------------------
extern "C" void kernel_launch(void* const* d_in, const int* in_sizes, int n_in,
                              void* d_out, int out_size, void* d_ws, size_t ws_size,
                              hipStream_t stream)
{
    const float* pre_spikes   = (const float*)d_in[0];
    const float* post_spikes  = (const float*)d_in[1];
    const float* weights      = (const float*)d_in[2];
    const float* pre_trace    = (const float*)d_in[3];
    const float* post_trace   = (const float*)d_in[4];
    const float* running_rate = (const float*)d_in[5];

    const int POST = in_sizes[5];
    const int PRE  = in_sizes[2] / POST;
    const int Bsz  = in_sizes[0] / PRE;
    const int K2   = 2 * Bsz;

    const size_t nCur   = (size_t)Bsz * POST;
    const size_t nW     = (size_t)POST * PRE;
    const size_t nPreT  = (size_t)Bsz * PRE;
    const size_t nPostT = (size_t)Bsz * POST;

    float* out_current    = (float*)d_out;
    float* out_weights    = out_current + nCur;
    float* out_pre_trace  = out_weights + nW;
    float* out_post_trace = out_pre_trace + nPreT;
    float* out_rate       = out_post_trace + nPostT;

    unsigned char* At     = (unsigned char*)d_ws;        // (POST x K2) fp8
    unsigned char* Bt     = At + (size_t)POST * K2;      // (PRE  x K2) fp8
    unsigned short* preBf = (unsigned short*)(Bt + (size_t)PRE * K2); // (B x PRE) bf16
    unsigned short* wBf   = preBf + nPreT;               // (POST x PRE) bf16

    const float dp = 0.95122942450071400910f;            // exp(-1/20)
    const float s  = dp * (0.01f / (float)Bsz);          // A+/-. * dp / B

    // 1) fused prep: traces + fp8 GEMM operands (one read per input)
    prep_post_kernel<<<dim3(POST / 64, Bsz / 64), 256, 0, stream>>>(
        post_spikes, post_trace, out_post_trace, At, POST, K2, Bsz, dp);
    prep_pre_kernel<<<dim3(PRE / 64, Bsz / 64), 256, 0, stream>>>(
        pre_spikes, pre_trace, out_pre_trace, Bt, preBf, PRE, K2, Bsz, dp);

    // 2) rate EMA
    rate_kernel<<<POST / 4, 256, 0, stream>>>(
        At, running_rate, out_rate, K2, Bsz);

    // 3) dw GEMM in MX-fp8 (M=POST, N=PRE, K=2B) + fused w/homeo/clip
    dw_fp8_kernel<<<dim3(PRE / 128, POST / 128), 256, 0, stream>>>(
        At, Bt, K2, PRE, s, weights, running_rate, out_weights, wBf);

    // 4) current GEMM bf16 (M=B, N=POST, K=PRE): pre_spikes @ new_w^T
    mfma_gemm_bt<<<dim3(POST / 128, Bsz / 128), 512, 0, stream>>>(
        preBf, wBf, PRE, POST, out_current);
}